// Round 3
// baseline (558.830 us; speedup 1.0000x reference)
//
#include <hip/hip_runtime.h>
#include <hip/hip_bf16.h>

typedef __bf16 bf16_t;
typedef __attribute__((ext_vector_type(8))) __bf16 bf16x8;
typedef __attribute__((ext_vector_type(4))) __bf16 bf16x4;
typedef __attribute__((ext_vector_type(4))) float f32x4;

#define E_DIM 256
#define J_DIM 32
#define B_DIM 4096
#define M_DIM (B_DIM * J_DIM)

// ---------------------------------------------------------------------------
// prep: [0,64): U->bf16   [64,128): W->bf16   [128,160): vkb[j][f]
// ---------------------------------------------------------------------------
__global__ __launch_bounds__(256) void prep_kernel(
    const float* __restrict__ keys, const float* __restrict__ U,
    const float* __restrict__ V, const float* __restrict__ W,
    const float* __restrict__ bias, float* __restrict__ vkb,
    bf16_t* __restrict__ Ubf, bf16_t* __restrict__ Wbf) {
    int tid = threadIdx.x, bid = blockIdx.x;
    if (bid < 128) {
        const float* src = (bid < 64) ? U : W;
        bf16_t* dst = (bid < 64) ? Ubf : Wbf;
        int idx = (bid & 63) * 1024 + tid * 4;
        f32x4 v = *(const f32x4*)(src + idx);
        bf16x4 o;
#pragma unroll
        for (int i = 0; i < 4; ++i) o[i] = (bf16_t)v[i];
        *(bf16x4*)(dst + idx) = o;
    } else {
        __shared__ float sk[E_DIM];
        int j = bid - 128, f = tid;
        sk[f] = keys[(size_t)j * E_DIM + f];
        __syncthreads();
        float acc = bias[f];
        for (int e = 0; e < E_DIM; e += 4) {
            f32x4 vv = *(const f32x4*)(V + (size_t)f * E_DIM + e);
#pragma unroll
            for (int i = 0; i < 4; ++i) acc += vv[i] * sk[e + i];
        }
        vkb[(size_t)j * E_DIM + f] = acc;
    }
}

// ---------------------------------------------------------------------------
// main: augmented GEMM  cand = [s ; x] @ [U ; W]^T + vkb   (K = 512, 16 kc)
//   A (state rows / broadcast x row): direct from global, line-coalesced.
//   B: double-buffered LDS via global_load_lds width=16 (async DMA, linear
//      dest -> no write conflicts, no VGPR round-trip). 1 barrier per kc.
//   gate = sigmoid(<x, s+k>) in fp32, keys folded in (L1-resident 32KB).
// ---------------------------------------------------------------------------
__global__ __launch_bounds__(256, 4) void memcell_kernel(
    const float* __restrict__ x, const float* __restrict__ state,
    const float* __restrict__ keys,
    const bf16_t* __restrict__ Ubf, const bf16_t* __restrict__ Wbf,
    const float* __restrict__ vkb, float* __restrict__ out) {
    __shared__ __align__(16) bf16_t sB[2][E_DIM][32];   // 2 x 16 KB, unpadded
    int tid = threadIdx.x;
    int w = tid >> 6, lane = tid & 63, quad = lane >> 4, l15 = lane & 15;
    int m0 = blockIdx.x * 64;
    int bw = (m0 >> 5) + (w >> 1);           // one b per wave
    int jrow = (w & 1) * 16 + l15;           // gate j for this lane's A-row
    f32x4 acc[16];
#pragma unroll
    for (int nt = 0; nt < 16; ++nt)
#pragma unroll
        for (int r = 0; r < 4; ++r) acc[nt][r] = 0.f;
    float gdot = 0.f;
    const float* sp = state + (size_t)(m0 + w * 16 + l15) * E_DIM + quad * 8;
    const float* xp = x + (size_t)bw * E_DIM + quad * 8;
    const float* kp = keys + (size_t)jrow * E_DIM + quad * 8;

    // async stage of one 256x32 B-tile (16 KB) into sB[buf]
    auto stage = [&](int buf, int kc) {
        const bf16_t* src = (kc < 8) ? Ubf : Wbf;
        const int koff = (kc & 7) * 32;
        bf16_t* lb = &sB[buf][0][0];
#pragma unroll
        for (int it = 0; it < 4; ++it) {
            int o = (it * 256 + tid) * 16;    // byte offset in tile (lane-linear)
            int n = o >> 6;                   // tile row (= output col f)
            int ce = (o & 63) >> 1;           // elem within row
            const bf16_t* g = src + (size_t)n * E_DIM + koff + ce;
            __builtin_amdgcn_global_load_lds(
                (const __attribute__((address_space(1))) unsigned int*)g,
                (__attribute__((address_space(3))) unsigned int*)(lb + (o >> 1)),
                16, 0, 0);
        }
    };

    stage(0, 0);
    __syncthreads();                          // drains vmcnt (compiler-inserted)

#pragma unroll
    for (int kc = 0; kc < 16; ++kc) {
        const int cur = kc & 1;
        if (kc < 15) stage(cur ^ 1, kc + 1);  // async prefetch next B-tile
        bf16x8 af;
        if (kc < 8) {                         // state part + fp32 gate dot
            const int k0 = kc * 32;
            f32x4 a0  = *(const f32x4*)(sp + k0);
            f32x4 a1  = *(const f32x4*)(sp + k0 + 4);
            f32x4 xv0 = *(const f32x4*)(xp + k0);
            f32x4 xv1 = *(const f32x4*)(xp + k0 + 4);
            f32x4 kv0 = *(const f32x4*)(kp + k0);
            f32x4 kv1 = *(const f32x4*)(kp + k0 + 4);
#pragma unroll
            for (int i = 0; i < 4; ++i) { af[i] = (bf16_t)a0[i]; af[4 + i] = (bf16_t)a1[i]; }
#pragma unroll
            for (int i = 0; i < 4; ++i) gdot += (a0[i] + kv0[i]) * xv0[i];
#pragma unroll
            for (int i = 0; i < 4; ++i) gdot += (a1[i] + kv1[i]) * xv1[i];
        } else {                              // x part: broadcast row of b
            const int k0 = (kc - 8) * 32;
            f32x4 xa = *(const f32x4*)(xp + k0);
            f32x4 xb = *(const f32x4*)(xp + k0 + 4);
#pragma unroll
            for (int i = 0; i < 4; ++i) { af[i] = (bf16_t)xa[i]; af[4 + i] = (bf16_t)xb[i]; }
        }
#pragma unroll
        for (int nt = 0; nt < 16; ++nt) {
            bf16x8 bfr = *(const bf16x8*)(&sB[cur][nt * 16 + l15][quad * 8]);
            acc[nt] = __builtin_amdgcn_mfma_f32_16x16x32_bf16(af, bfr, acc[nt], 0, 0, 0);
        }
        __syncthreads();                      // read-done + next stage landed
    }

    // reduce gate dot across quads (k was split quad-wise)
    gdot += __shfl_xor(gdot, 16);
    gdot += __shfl_xor(gdot, 32);
    float gv = 1.f / (1.f + expf(-gdot));
    float gate[4];
#pragma unroll
    for (int r = 0; r < 4; ++r) gate[r] = __shfl(gv, quad * 4 + r);
    // epilogue: C/D layout row = quad*4+r, col = nt*16+l15
    float sumsq[4] = {0.f, 0.f, 0.f, 0.f};
#pragma unroll
    for (int nt = 0; nt < 16; ++nt) {
        int f = nt * 16 + l15;
#pragma unroll
        for (int r = 0; r < 4; ++r) {
            int rl = quad * 4 + r;
            int jidx = (w & 1) * 16 + rl;
            float c = acc[nt][r] + vkb[(size_t)jidx * E_DIM + f];
            c = fmaxf(c, 0.f);
            float sv = state[(size_t)(m0 + w * 16 + rl) * E_DIM + f]; // LLC-hot re-read
            float t = fmaf(gate[r], c, sv);
            acc[nt][r] = t;
            sumsq[r] += t * t;
        }
    }
    float rn[4];
#pragma unroll
    for (int r = 0; r < 4; ++r) {
        float s2 = sumsq[r];
        s2 += __shfl_xor(s2, 1);
        s2 += __shfl_xor(s2, 2);
        s2 += __shfl_xor(s2, 4);
        s2 += __shfl_xor(s2, 8);
        rn[r] = 1.f / (sqrtf(s2) + 1e-8f);
    }
#pragma unroll
    for (int nt = 0; nt < 16; ++nt)
#pragma unroll
        for (int r = 0; r < 4; ++r)
            out[(size_t)(m0 + w * 16 + quad * 4 + r) * E_DIM + nt * 16 + l15] =
                acc[nt][r] * rn[r];
}

extern "C" void kernel_launch(void* const* d_in, const int* in_sizes, int n_in,
                              void* d_out, int out_size, void* d_ws, size_t ws_size,
                              hipStream_t stream) {
    const float* x     = (const float*)d_in[0];
    const float* state = (const float*)d_in[1];
    const float* keys  = (const float*)d_in[2];
    const float* U     = (const float*)d_in[3];
    const float* V     = (const float*)d_in[4];
    const float* W     = (const float*)d_in[5];
    const float* bias  = (const float*)d_in[6];
    float* out = (float*)d_out;

    float* wsf = (float*)d_ws;
    float* vkb = wsf;                                     // 32*256  fp32 = 32 KB
    bf16_t* Ubf = (bf16_t*)(vkb + (size_t)J_DIM * E_DIM); // 256*256 bf16 = 128 KB
    bf16_t* Wbf = Ubf + (size_t)E_DIM * E_DIM;            // 256*256 bf16 = 128 KB

    prep_kernel<<<160, 256, 0, stream>>>(keys, U, V, W, bias, vkb, Ubf, Wbf);
    memcell_kernel<<<M_DIM / 64, 256, 0, stream>>>(x, state, keys, Ubf, Wbf, vkb, out);
}

// Round 4
// 393.742 us; speedup vs baseline: 1.4193x; 1.4193x over previous
//
#include <hip/hip_runtime.h>
#include <hip/hip_bf16.h>

typedef __bf16 bf16_t;
typedef __attribute__((ext_vector_type(8))) __bf16 bf16x8;
typedef __attribute__((ext_vector_type(4))) __bf16 bf16x4;
typedef __attribute__((ext_vector_type(4))) float f32x4;

#define E_DIM 256
#define J_DIM 32
#define B_DIM 4096
#define M_DIM (B_DIM * J_DIM)
#define BM 64
#define BK 32
#define LDA 40   // bf16: BK + 8 pad (16B-aligned rows, spreads banks)
#define LDB 40
#define LDAF 33  // fp32: BK + 1 pad (max 2-way bank alias = free)

// ---------------------------------------------------------------------------
// prep: [0,64): U->bf16   [64,128): W->bf16   [128,160): vkb[j][f]
// ---------------------------------------------------------------------------
__global__ __launch_bounds__(256) void prep_kernel(
    const float* __restrict__ keys, const float* __restrict__ U,
    const float* __restrict__ V, const float* __restrict__ W,
    const float* __restrict__ bias, float* __restrict__ vkb,
    bf16_t* __restrict__ Ubf, bf16_t* __restrict__ Wbf) {
    int tid = threadIdx.x, bid = blockIdx.x;
    if (bid < 128) {
        const float* src = (bid < 64) ? U : W;
        bf16_t* dst = (bid < 64) ? Ubf : Wbf;
        int idx = (bid & 63) * 1024 + tid * 4;
        f32x4 v = *(const f32x4*)(src + idx);
        bf16x4 o;
#pragma unroll
        for (int i = 0; i < 4; ++i) o[i] = (bf16_t)v[i];
        *(bf16x4*)(dst + idx) = o;
    } else {
        __shared__ float sk[E_DIM];
        int j = bid - 128, f = tid;
        sk[f] = keys[(size_t)j * E_DIM + f];
        __syncthreads();
        float acc = bias[f];
        for (int e = 0; e < E_DIM; e += 4) {
            f32x4 vv = *(const f32x4*)(V + (size_t)f * E_DIM + e);
#pragma unroll
            for (int i = 0; i < 4; ++i) acc += vv[i] * sk[e + i];
        }
        vkb[(size_t)j * E_DIM + f] = acc;
    }
}

// ---------------------------------------------------------------------------
// main (round-0 structure + fused wx + folded xk):
//   augmented GEMM: cand = [s ; x] @ [U ; W]^T + vkb   (K=512, 16 kc)
//     kc 0..7 : A = state rows (also fp32 copy to sAf for the gate dot)
//     kc 8..15: A = broadcast x row of each b (read from sXf in LDS)
//   B staged from pre-converted bf16 (Ubf/Wbf, L2-resident), tid-linear
//   register->ds_write staging, 2 barriers/kc (proven round-0 discipline).
//   gate = sigmoid(<x, s+k>) in fp32; keys rows read direct (L1-hot 32 KB).
// ---------------------------------------------------------------------------
__global__ __launch_bounds__(256) void memcell_kernel(
    const float* __restrict__ x, const float* __restrict__ state,
    const float* __restrict__ keys,
    const bf16_t* __restrict__ Ubf, const bf16_t* __restrict__ Wbf,
    const float* __restrict__ vkb, float* __restrict__ out) {
    __shared__ __align__(16) bf16_t sA[BM][LDA];
    __shared__ __align__(16) bf16_t sB[E_DIM][LDB];
    __shared__ __align__(16) float sAf[BM][LDAF];   // fp32 state tile (gate dot)
    __shared__ __align__(16) float sXf[2][E_DIM];   // fp32 x rows (gate + kc>=8 A)
    int tid = threadIdx.x;
    int w = tid >> 6, lane = tid & 63, quad = lane >> 4, l15 = lane & 15;
    int m0 = blockIdx.x * BM;
    int b0 = m0 >> 5;                        // block covers b0, b0+1
    int jrow = (w & 1) * 16 + l15;           // gate j for this lane's A-row
    f32x4 acc[16];
#pragma unroll
    for (int nt = 0; nt < 16; ++nt)
#pragma unroll
        for (int r = 0; r < 4; ++r) acc[nt][r] = 0.f;
    float gdot = 0.f;
    if (tid < 64) {                          // stage the 2 x-rows (fp32)
        int bb = tid >> 5, p = tid & 31;
        f32x4 xa = *(const f32x4*)(x + (size_t)(b0 + bb) * E_DIM + p * 8);
        f32x4 xb = *(const f32x4*)(x + (size_t)(b0 + bb) * E_DIM + p * 8 + 4);
        *(f32x4*)(&sXf[bb][p * 8]) = xa;
        *(f32x4*)(&sXf[bb][p * 8 + 4]) = xb;
    }
    int arow = tid >> 2, akk = (tid & 3) * 8;
    const float* kp = keys + (size_t)jrow * E_DIM + quad * 8;
    for (int kc = 0; kc < 16; ++kc) {
        int k0 = (kc & 7) * BK;
        __syncthreads();
        if (kc < 8) {   // A = state tile: fp32 copy for gate dot + bf16 for MFMA
            const float* sp = state + (size_t)(m0 + arow) * E_DIM + k0 + akk;
            f32x4 a = *(const f32x4*)sp;
            f32x4 b = *(const f32x4*)(sp + 4);
            *(f32x4*)(&sAf[arow][akk]) = a;
            *(f32x4*)(&sAf[arow][akk + 4]) = b;
            bf16x8 r;
            r[0] = (bf16_t)a[0]; r[1] = (bf16_t)a[1]; r[2] = (bf16_t)a[2]; r[3] = (bf16_t)a[3];
            r[4] = (bf16_t)b[0]; r[5] = (bf16_t)b[1]; r[6] = (bf16_t)b[2]; r[7] = (bf16_t)b[3];
            *(bf16x8*)(&sA[arow][akk]) = r;
        } else {        // A = broadcast x row of this b (from LDS copy)
            f32x4 a = *(const f32x4*)(&sXf[arow >> 5][k0 + akk]);
            f32x4 b = *(const f32x4*)(&sXf[arow >> 5][k0 + akk + 4]);
            bf16x8 r;
            r[0] = (bf16_t)a[0]; r[1] = (bf16_t)a[1]; r[2] = (bf16_t)a[2]; r[3] = (bf16_t)a[3];
            r[4] = (bf16_t)b[0]; r[5] = (bf16_t)b[1]; r[6] = (bf16_t)b[2]; r[7] = (bf16_t)b[3];
            *(bf16x8*)(&sA[arow][akk]) = r;
        }
        {   // B stage: pre-converted bf16, tid-linear coalesced
            const bf16_t* src = (kc < 8) ? Ubf : Wbf;
#pragma unroll
            for (int it = 0; it < 4; ++it) {
                int t = it * 256 + tid;
                int n = t >> 2, kk = (t & 3) * 8;
                *(bf16x8*)(&sB[n][kk]) =
                    *(const bf16x8*)(src + (size_t)n * E_DIM + k0 + kk);
            }
        }
        __syncthreads();
        // A-frag: row = w*16+l15 (wave owns 16 full rows), k = k0 + quad*8 + i
        bf16x8 af = *(const bf16x8*)(&sA[w * 16 + l15][quad * 8]);
        if (kc < 8) {   // fp32 gate dot: (s + k) . x over this k-slice
            f32x4 kv0 = *(const f32x4*)(kp + k0);
            f32x4 kv1 = *(const f32x4*)(kp + k0 + 4);
#pragma unroll
            for (int i = 0; i < 4; ++i)
                gdot += (sAf[w * 16 + l15][quad * 8 + i] + kv0[i]) *
                        sXf[w >> 1][k0 + quad * 8 + i];
#pragma unroll
            for (int i = 0; i < 4; ++i)
                gdot += (sAf[w * 16 + l15][quad * 8 + 4 + i] + kv1[i]) *
                        sXf[w >> 1][k0 + quad * 8 + 4 + i];
        }
#pragma unroll
        for (int nt = 0; nt < 16; ++nt) {
            bf16x8 bfr = *(const bf16x8*)(&sB[nt * 16 + l15][quad * 8]);
            acc[nt] = __builtin_amdgcn_mfma_f32_16x16x32_bf16(af, bfr, acc[nt], 0, 0, 0);
        }
    }
    // reduce gate dot across quads (k was split quad-wise): lanes sharing l15
    gdot += __shfl_xor(gdot, 16);
    gdot += __shfl_xor(gdot, 32);
    float gv = 1.f / (1.f + expf(-gdot));
    float gate[4];
#pragma unroll
    for (int r = 0; r < 4; ++r) gate[r] = __shfl(gv, quad * 4 + r);
    // epilogue: C/D layout row = quad*4+r, col = nt*16+l15
    float sumsq[4] = {0.f, 0.f, 0.f, 0.f};
#pragma unroll
    for (int nt = 0; nt < 16; ++nt) {
        int f = nt * 16 + l15;
#pragma unroll
        for (int r = 0; r < 4; ++r) {
            int rl = quad * 4 + r;
            int jidx = (w & 1) * 16 + rl;
            float c = acc[nt][r] + vkb[(size_t)jidx * E_DIM + f];
            c = fmaxf(c, 0.f);
            float sv = state[(size_t)(m0 + w * 16 + rl) * E_DIM + f]; // LLC-hot re-read
            float t = fmaf(gate[r], c, sv);
            acc[nt][r] = t;
            sumsq[r] += t * t;
        }
    }
    float rn[4];
#pragma unroll
    for (int r = 0; r < 4; ++r) {
        float s2 = sumsq[r];
        s2 += __shfl_xor(s2, 1);
        s2 += __shfl_xor(s2, 2);
        s2 += __shfl_xor(s2, 4);
        s2 += __shfl_xor(s2, 8);
        rn[r] = 1.f / (sqrtf(s2) + 1e-8f);
    }
#pragma unroll
    for (int nt = 0; nt < 16; ++nt)
#pragma unroll
        for (int r = 0; r < 4; ++r)
            out[(size_t)(m0 + w * 16 + quad * 4 + r) * E_DIM + nt * 16 + l15] =
                acc[nt][r] * rn[r];
}

extern "C" void kernel_launch(void* const* d_in, const int* in_sizes, int n_in,
                              void* d_out, int out_size, void* d_ws, size_t ws_size,
                              hipStream_t stream) {
    const float* x     = (const float*)d_in[0];
    const float* state = (const float*)d_in[1];
    const float* keys  = (const float*)d_in[2];
    const float* U     = (const float*)d_in[3];
    const float* V     = (const float*)d_in[4];
    const float* W     = (const float*)d_in[5];
    const float* bias  = (const float*)d_in[6];
    float* out = (float*)d_out;

    float* wsf = (float*)d_ws;
    float* vkb = wsf;                                     // 32*256  fp32 = 32 KB
    bf16_t* Ubf = (bf16_t*)(vkb + (size_t)J_DIM * E_DIM); // 256*256 bf16 = 128 KB
    bf16_t* Wbf = Ubf + (size_t)E_DIM * E_DIM;            // 256*256 bf16 = 128 KB

    prep_kernel<<<160, 256, 0, stream>>>(keys, U, V, W, bias, vkb, Ubf, Wbf);
    memcell_kernel<<<M_DIM / BM, 256, 0, stream>>>(x, state, keys, Ubf, Wbf, vkb, out);
}

// Round 5
// 378.947 us; speedup vs baseline: 1.4747x; 1.0390x over previous
//
#include <hip/hip_runtime.h>
#include <hip/hip_bf16.h>

typedef __bf16 bf16_t;
typedef __attribute__((ext_vector_type(8))) __bf16 bf16x8;
typedef __attribute__((ext_vector_type(4))) __bf16 bf16x4;
typedef __attribute__((ext_vector_type(4))) float f32x4;

#define E_DIM 256
#define J_DIM 32
#define B_DIM 4096
#define M_DIM (B_DIM * J_DIM)
#define BM 64
#define BK 32
#define LDA 40   // bf16: BK + 8 pad (16B-aligned rows, spreads banks)
#define LDB 40

// load 8 consecutive fp32, convert to bf16x8 (RNE)
__device__ inline bf16x8 cvt8(const float* __restrict__ p) {
    f32x4 a = *(const f32x4*)p;
    f32x4 b = *(const f32x4*)(p + 4);
    bf16x8 r;
    r[0] = (bf16_t)a[0]; r[1] = (bf16_t)a[1]; r[2] = (bf16_t)a[2]; r[3] = (bf16_t)a[3];
    r[4] = (bf16_t)b[0]; r[5] = (bf16_t)b[1]; r[6] = (bf16_t)b[2]; r[7] = (bf16_t)b[3];
    return r;
}

// ---------------------------------------------------------------------------
// prep: [0,64): U->bf16   [64,128): W->bf16   [128,160): vkb[j][f]
// ---------------------------------------------------------------------------
__global__ __launch_bounds__(256) void prep_kernel(
    const float* __restrict__ keys, const float* __restrict__ U,
    const float* __restrict__ V, const float* __restrict__ W,
    const float* __restrict__ bias, float* __restrict__ vkb,
    bf16_t* __restrict__ Ubf, bf16_t* __restrict__ Wbf) {
    int tid = threadIdx.x, bid = blockIdx.x;
    if (bid < 128) {
        const float* src = (bid < 64) ? U : W;
        bf16_t* dst = (bid < 64) ? Ubf : Wbf;
        int idx = (bid & 63) * 1024 + tid * 4;
        f32x4 v = *(const f32x4*)(src + idx);
        bf16x4 o;
#pragma unroll
        for (int i = 0; i < 4; ++i) o[i] = (bf16_t)v[i];
        *(bf16x4*)(dst + idx) = o;
    } else {
        __shared__ float sk[E_DIM];
        int j = bid - 128, f = tid;
        sk[f] = keys[(size_t)j * E_DIM + f];
        __syncthreads();
        float acc = bias[f];
        for (int e = 0; e < E_DIM; e += 4) {
            f32x4 vv = *(const f32x4*)(V + (size_t)f * E_DIM + e);
#pragma unroll
            for (int i = 0; i < 4; ++i) acc += vv[i] * sk[e + i];
        }
        vkb[(size_t)j * E_DIM + f] = acc;
    }
}

// ---------------------------------------------------------------------------
// wx[b][f] = sum_e W[f,e]*x[b,e] — well-shaped: 256 blocks (64 m x 4 n tiles)
//   BM=64 x BN=64, wave w owns 16 m-rows x 64 n-cols (4 MFMA accs).
// ---------------------------------------------------------------------------
__global__ __launch_bounds__(256) void wx_kernel(const float* __restrict__ x,
                                                 const bf16_t* __restrict__ Wbf,
                                                 float* __restrict__ wx) {
    __shared__ __align__(16) bf16_t sA[BM][LDA];
    __shared__ __align__(16) bf16_t sBw[64][LDB];
    int tid = threadIdx.x;
    int w = tid >> 6, lane = tid & 63, quad = lane >> 4, l15 = lane & 15;
    int m0 = (blockIdx.x >> 2) * BM, n0 = (blockIdx.x & 3) * 64;
    f32x4 acc[4];
#pragma unroll
    for (int nt = 0; nt < 4; ++nt)
#pragma unroll
        for (int r = 0; r < 4; ++r) acc[nt][r] = 0.f;
    int arow = tid >> 2, akk = (tid & 3) * 8;
    for (int kc = 0; kc < 8; ++kc) {
        int k0 = kc * BK;
        __syncthreads();
        *(bf16x8*)(&sA[arow][akk]) = cvt8(x + (size_t)(m0 + arow) * E_DIM + k0 + akk);
        *(bf16x8*)(&sBw[arow][akk]) =
            *(const bf16x8*)(Wbf + (size_t)(n0 + arow) * E_DIM + k0 + akk);
        __syncthreads();
        bf16x8 af = *(const bf16x8*)(&sA[w * 16 + l15][quad * 8]);
#pragma unroll
        for (int nt = 0; nt < 4; ++nt) {
            bf16x8 bfr = *(const bf16x8*)(&sBw[nt * 16 + l15][quad * 8]);
            acc[nt] = __builtin_amdgcn_mfma_f32_16x16x32_bf16(af, bfr, acc[nt], 0, 0, 0);
        }
    }
#pragma unroll
    for (int nt = 0; nt < 4; ++nt)
#pragma unroll
        for (int r = 0; r < 4; ++r)
            wx[(size_t)(m0 + w * 16 + quad * 4 + r) * E_DIM + n0 + nt * 16 + l15] =
                acc[nt][r];
}

// ---------------------------------------------------------------------------
// main (round-0 proven structure, K=256):
//   cand = s @ U^T + wx[b] + vkb[j];  gate = sigmoid(<x, s+k>) fp32;
//   out = normalize(s + gate*relu(cand))
//   B from pre-converted Ubf; gate-dot state slice read direct from global
//   (L1-hot: stagers fetch the same lines this iteration) -> no sAf tile.
// ---------------------------------------------------------------------------
__global__ __launch_bounds__(256) void memcell_kernel(
    const float* __restrict__ x, const float* __restrict__ state,
    const float* __restrict__ keys, const bf16_t* __restrict__ Ubf,
    const float* __restrict__ wx, const float* __restrict__ vkb,
    float* __restrict__ out) {
    __shared__ __align__(16) bf16_t sA[BM][LDA];
    __shared__ __align__(16) bf16_t sB[E_DIM][LDB];
    __shared__ __align__(16) float sXf[2][E_DIM];   // fp32 x rows (gate dot)
    int tid = threadIdx.x;
    int w = tid >> 6, lane = tid & 63, quad = lane >> 4, l15 = lane & 15;
    int m0 = blockIdx.x * BM;
    int b0 = m0 >> 5;                        // block covers b0, b0+1
    int jrow = (w & 1) * 16 + l15;           // gate j for this lane's A-row
    f32x4 acc[16];
#pragma unroll
    for (int nt = 0; nt < 16; ++nt)
#pragma unroll
        for (int r = 0; r < 4; ++r) acc[nt][r] = 0.f;
    float gdot = 0.f;
    if (tid < 64) {                          // stage the 2 x-rows (fp32)
        int bb = tid >> 5, p = tid & 31;
        f32x4 xa = *(const f32x4*)(x + (size_t)(b0 + bb) * E_DIM + p * 8);
        f32x4 xb = *(const f32x4*)(x + (size_t)(b0 + bb) * E_DIM + p * 8 + 4);
        *(f32x4*)(&sXf[bb][p * 8]) = xa;
        *(f32x4*)(&sXf[bb][p * 8 + 4]) = xb;
    }
    int arow = tid >> 2, akk = (tid & 3) * 8;
    const float* kp = keys + (size_t)jrow * E_DIM + quad * 8;
    const float* sgp = state + (size_t)(m0 + w * 16 + l15) * E_DIM + quad * 8;
    for (int kc = 0; kc < 8; ++kc) {
        int k0 = kc * BK;
        __syncthreads();
        *(bf16x8*)(&sA[arow][akk]) = cvt8(state + (size_t)(m0 + arow) * E_DIM + k0 + akk);
#pragma unroll
        for (int it = 0; it < 4; ++it) {
            int t = it * 256 + tid;
            int n = t >> 2, kk = (t & 3) * 8;
            *(bf16x8*)(&sB[n][kk]) =
                *(const bf16x8*)(Ubf + (size_t)n * E_DIM + k0 + kk);
        }
        __syncthreads();
        // A-frag: row = w*16+l15 (wave owns 16 full rows), k = k0 + quad*8 + i
        bf16x8 af = *(const bf16x8*)(&sA[w * 16 + l15][quad * 8]);
#pragma unroll
        for (int nt = 0; nt < 16; ++nt) {
            bf16x8 bfr = *(const bf16x8*)(&sB[nt * 16 + l15][quad * 8]);
            acc[nt] = __builtin_amdgcn_mfma_f32_16x16x32_bf16(af, bfr, acc[nt], 0, 0, 0);
        }
        {   // fp32 gate dot: (s + k) . x over this k-slice (state L1-hot)
            f32x4 s0 = *(const f32x4*)(sgp + k0);
            f32x4 s1 = *(const f32x4*)(sgp + k0 + 4);
            f32x4 kv0 = *(const f32x4*)(kp + k0);
            f32x4 kv1 = *(const f32x4*)(kp + k0 + 4);
#pragma unroll
            for (int i = 0; i < 4; ++i)
                gdot += (s0[i] + kv0[i]) * sXf[w >> 1][k0 + quad * 8 + i];
#pragma unroll
            for (int i = 0; i < 4; ++i)
                gdot += (s1[i] + kv1[i]) * sXf[w >> 1][k0 + quad * 8 + 4 + i];
        }
    }
    // reduce gate dot across quads (k was split quad-wise): lanes sharing l15
    gdot += __shfl_xor(gdot, 16);
    gdot += __shfl_xor(gdot, 32);
    float gv = 1.f / (1.f + expf(-gdot));
    float gate[4];
#pragma unroll
    for (int r = 0; r < 4; ++r) gate[r] = __shfl(gv, quad * 4 + r);
    // epilogue: C/D layout row = quad*4+r, col = nt*16+l15
    int bw = b0 + (w >> 1);
    float sumsq[4] = {0.f, 0.f, 0.f, 0.f};
    const float* wxrow = wx + (size_t)bw * E_DIM;
#pragma unroll
    for (int nt = 0; nt < 16; ++nt) {
        int f = nt * 16 + l15;
        float wxf = wxrow[f];
#pragma unroll
        for (int r = 0; r < 4; ++r) {
            int rl = quad * 4 + r;
            int jidx = (w & 1) * 16 + rl;
            float c = acc[nt][r] + wxf + vkb[(size_t)jidx * E_DIM + f];
            c = fmaxf(c, 0.f);
            float sv = state[(size_t)(m0 + w * 16 + rl) * E_DIM + f]; // LLC-hot re-read
            float t = fmaf(gate[r], c, sv);
            acc[nt][r] = t;
            sumsq[r] += t * t;
        }
    }
    float rn[4];
#pragma unroll
    for (int r = 0; r < 4; ++r) {
        float s2 = sumsq[r];
        s2 += __shfl_xor(s2, 1);
        s2 += __shfl_xor(s2, 2);
        s2 += __shfl_xor(s2, 4);
        s2 += __shfl_xor(s2, 8);
        rn[r] = 1.f / (sqrtf(s2) + 1e-8f);
    }
#pragma unroll
    for (int nt = 0; nt < 16; ++nt)
#pragma unroll
        for (int r = 0; r < 4; ++r)
            out[(size_t)(m0 + w * 16 + quad * 4 + r) * E_DIM + nt * 16 + l15] =
                acc[nt][r] * rn[r];
}

extern "C" void kernel_launch(void* const* d_in, const int* in_sizes, int n_in,
                              void* d_out, int out_size, void* d_ws, size_t ws_size,
                              hipStream_t stream) {
    const float* x     = (const float*)d_in[0];
    const float* state = (const float*)d_in[1];
    const float* keys  = (const float*)d_in[2];
    const float* U     = (const float*)d_in[3];
    const float* V     = (const float*)d_in[4];
    const float* W     = (const float*)d_in[5];
    const float* bias  = (const float*)d_in[6];
    float* out = (float*)d_out;

    float* wsf = (float*)d_ws;
    float* wx  = wsf;                                     // 4096*256 fp32 = 4 MB
    float* vkb = wx + (size_t)B_DIM * E_DIM;              // 32*256  fp32 = 32 KB
    bf16_t* Ubf = (bf16_t*)(vkb + (size_t)J_DIM * E_DIM); // 256*256 bf16 = 128 KB
    bf16_t* Wbf = Ubf + (size_t)E_DIM * E_DIM;            // 256*256 bf16 = 128 KB

    prep_kernel<<<160, 256, 0, stream>>>(keys, U, V, W, bias, vkb, Ubf, Wbf);
    wx_kernel<<<256, 256, 0, stream>>>(x, Wbf, wx);
    memcell_kernel<<<M_DIM / BM, 256, 0, stream>>>(x, state, keys, Ubf, wx, vkb, out);
}

// Round 6
// 309.371 us; speedup vs baseline: 1.8063x; 1.2249x over previous
//
#include <hip/hip_runtime.h>
#include <hip/hip_bf16.h>

typedef __bf16 bf16_t;
typedef __attribute__((ext_vector_type(8))) __bf16 bf16x8;
typedef __attribute__((ext_vector_type(4))) float f32x4;

#define E_DIM 256
#define J_DIM 32
#define B_DIM 4096
#define M_DIM (B_DIM * J_DIM)
#define BM 64
#define BK 32
#define LDA 40   // bf16: BK + 8 pad (16B-aligned, spreads banks)
#define LDB 40
#define LDAF 33  // fp32: BK + 1 pad (max 2-way bank alias = free)

#define XK_LDA (E_DIM + 4)  // fp32 xk tile pad: 32-way -> 4-way bank alias

// load 8 consecutive fp32, convert to bf16x8 (RNE)
__device__ inline bf16x8 cvt8(const float* __restrict__ p) {
    f32x4 a = *(const f32x4*)p;
    f32x4 b = *(const f32x4*)(p + 4);
    bf16x8 r;
    r[0] = (bf16_t)a[0]; r[1] = (bf16_t)a[1]; r[2] = (bf16_t)a[2]; r[3] = (bf16_t)a[3];
    r[4] = (bf16_t)b[0]; r[5] = (bf16_t)b[1]; r[6] = (bf16_t)b[2]; r[7] = (bf16_t)b[3];
    return r;
}

// ---------------------------------------------------------------------------
// fused: [0,512): xk[b][j] = <x_b, k_j>  (8 b per block, padded LDS)
//        [512,544): vkb[j][f] = bias[f] + sum_e V[f,e]*keys[j,e]
// ---------------------------------------------------------------------------
__global__ __launch_bounds__(256) void xkvkb_kernel(
    const float* __restrict__ x, const float* __restrict__ keys,
    const float* __restrict__ V, const float* __restrict__ bias,
    float* __restrict__ xk, float* __restrict__ vkb) {
    __shared__ float smem[(J_DIM + 8) * XK_LDA];   // 40*260 fp32 = 41.6 KB
    int tid = threadIdx.x, bid = blockIdx.x;
    if (bid < 512) {
        float* sK = smem;                          // [32][XK_LDA]
        float* sX = smem + J_DIM * XK_LDA;         // [8][XK_LDA]
        int b0 = bid * 8;
#pragma unroll
        for (int it = 0; it < 8; ++it) {
            int t = it * 256 + tid;
            int r = t >> 6, c = (t & 63) * 4;
            *(f32x4*)(sK + r * XK_LDA + c) = *(const f32x4*)(keys + (size_t)r * E_DIM + c);
        }
#pragma unroll
        for (int it = 0; it < 2; ++it) {
            int t = it * 256 + tid;
            int r = t >> 6, c = (t & 63) * 4;
            *(f32x4*)(sX + r * XK_LDA + c) =
                *(const f32x4*)(x + (size_t)b0 * E_DIM + (size_t)r * E_DIM + c);
        }
        __syncthreads();
        int j = tid & 31, bl = tid >> 5;
        float acc = 0.f;
        for (int e = 0; e < E_DIM; e += 4) {
            f32x4 xv = *(const f32x4*)(sX + bl * XK_LDA + e);
            f32x4 kv = *(const f32x4*)(sK + j * XK_LDA + e);
#pragma unroll
            for (int i = 0; i < 4; ++i) acc += xv[i] * kv[i];
        }
        xk[(size_t)(b0 + bl) * J_DIM + j] = acc;
    } else {
        int j = bid - 512, f = tid;
        float* sk = smem;
        sk[f] = keys[(size_t)j * E_DIM + f];
        __syncthreads();
        float acc = bias[f];
        for (int e = 0; e < E_DIM; e += 4) {
            f32x4 vv = *(const f32x4*)(V + (size_t)f * E_DIM + e);
#pragma unroll
            for (int i = 0; i < 4; ++i) acc += vv[i] * sk[e + i];
        }
        vkb[(size_t)j * E_DIM + f] = acc;
    }
}

// ---------------------------------------------------------------------------
// wx[b][f] = sum_e W[f,e]*x[b,e] — round-0 math (cvt8 from fp32 W), but
// well-shaped: 256 blocks (64 m-tiles x 4 n-tiles), BM=64 x BN=64.
// Wave w owns 16 m-rows x 64 n-cols (4 MFMA accs).
// ---------------------------------------------------------------------------
__global__ __launch_bounds__(256) void wx_kernel(const float* __restrict__ x,
                                                 const float* __restrict__ W,
                                                 float* __restrict__ wx) {
    __shared__ __align__(16) bf16_t sA[BM][LDA];
    __shared__ __align__(16) bf16_t sBw[64][LDB];
    int tid = threadIdx.x;
    int w = tid >> 6, lane = tid & 63, quad = lane >> 4, l15 = lane & 15;
    int m0 = (blockIdx.x >> 2) * BM, n0 = (blockIdx.x & 3) * 64;
    f32x4 acc[4];
#pragma unroll
    for (int nt = 0; nt < 4; ++nt)
#pragma unroll
        for (int r = 0; r < 4; ++r) acc[nt][r] = 0.f;
    int arow = tid >> 2, akk = (tid & 3) * 8;
    for (int kc = 0; kc < 8; ++kc) {
        int k0 = kc * BK;
        __syncthreads();
        *(bf16x8*)(&sA[arow][akk]) = cvt8(x + (size_t)(m0 + arow) * E_DIM + k0 + akk);
        *(bf16x8*)(&sBw[arow][akk]) = cvt8(W + (size_t)(n0 + arow) * E_DIM + k0 + akk);
        __syncthreads();
        bf16x8 af = *(const bf16x8*)(&sA[w * 16 + l15][quad * 8]);
#pragma unroll
        for (int nt = 0; nt < 4; ++nt) {
            bf16x8 bfr = *(const bf16x8*)(&sBw[nt * 16 + l15][quad * 8]);
            acc[nt] = __builtin_amdgcn_mfma_f32_16x16x32_bf16(af, bfr, acc[nt], 0, 0, 0);
        }
    }
#pragma unroll
    for (int nt = 0; nt < 4; ++nt)
#pragma unroll
        for (int r = 0; r < 4; ++r)
            wx[(size_t)(m0 + w * 16 + quad * 4 + r) * E_DIM + n0 + nt * 16 + l15] =
                acc[nt][r];
}

// ---------------------------------------------------------------------------
// main: EXACT round-0 structure (115 µs measured), dead sX tile removed.
// cand = s@U^T + wx[b] + vkb[j]; gate = sigmoid(<x,s>_fp32 + xk);
// out = normalize(s + gate*relu(cand))
// ---------------------------------------------------------------------------
__global__ __launch_bounds__(256) void memcell_kernel(
    const float* __restrict__ x, const float* __restrict__ state,
    const float* __restrict__ U, const float* __restrict__ wx,
    const float* __restrict__ xk, const float* __restrict__ vkb,
    float* __restrict__ out) {
    __shared__ __align__(16) bf16_t sA[BM][LDA];
    __shared__ __align__(16) bf16_t sB[E_DIM][LDB];
    __shared__ __align__(16) float sAf[BM][LDAF];   // fp32 state tile (gate dot)
    __shared__ __align__(16) float sXf[2][E_DIM];   // fp32 x rows     (gate dot)
    int tid = threadIdx.x;
    int w = tid >> 6, lane = tid & 63, quad = lane >> 4, l15 = lane & 15;
    int m0 = blockIdx.x * BM;
    int b0 = m0 >> 5;                       // block covers b0, b0+1
    f32x4 acc[16];
#pragma unroll
    for (int nt = 0; nt < 16; ++nt)
#pragma unroll
        for (int r = 0; r < 4; ++r) acc[nt][r] = 0.f;
    float gdot = 0.f;
    if (tid < 64) {                          // stage the 2 x-rows (fp32)
        int bb = tid >> 5, p = tid & 31;
        f32x4 xa = *(const f32x4*)(x + (size_t)(b0 + bb) * E_DIM + p * 8);
        f32x4 xb = *(const f32x4*)(x + (size_t)(b0 + bb) * E_DIM + p * 8 + 4);
        *(f32x4*)(&sXf[bb][p * 8]) = xa;
        *(f32x4*)(&sXf[bb][p * 8 + 4]) = xb;
    }
    int arow = tid >> 2, akk = (tid & 3) * 8;
    for (int kc = 0; kc < 8; ++kc) {
        int k0 = kc * BK;
        __syncthreads();
        {   // stage state tile: fp32 copy for gate dot + bf16 for MFMA
            const float* sp = state + (size_t)(m0 + arow) * E_DIM + k0 + akk;
            f32x4 a = *(const f32x4*)sp;
            f32x4 b = *(const f32x4*)(sp + 4);
            *(f32x4*)(&sAf[arow][akk]) = a;
            *(f32x4*)(&sAf[arow][akk + 4]) = b;
            bf16x8 r;
            r[0] = (bf16_t)a[0]; r[1] = (bf16_t)a[1]; r[2] = (bf16_t)a[2]; r[3] = (bf16_t)a[3];
            r[4] = (bf16_t)b[0]; r[5] = (bf16_t)b[1]; r[6] = (bf16_t)b[2]; r[7] = (bf16_t)b[3];
            *(bf16x8*)(&sA[arow][akk]) = r;
        }
#pragma unroll
        for (int it = 0; it < 4; ++it) {
            int t = it * 256 + tid;
            int n = t >> 2, kk = (t & 3) * 8;
            *(bf16x8*)(&sB[n][kk]) = cvt8(U + (size_t)n * E_DIM + k0 + kk);
        }
        __syncthreads();
        // A-frag: row = w*16+l15 (wave owns 16 full rows), k = k0 + quad*8 + j
        bf16x8 af = *(const bf16x8*)(&sA[w * 16 + l15][quad * 8]);
#pragma unroll
        for (int i = 0; i < 8; ++i)
            gdot += sAf[w * 16 + l15][quad * 8 + i] * sXf[w >> 1][k0 + quad * 8 + i];
#pragma unroll
        for (int nt = 0; nt < 16; ++nt) {
            bf16x8 bfr = *(const bf16x8*)(&sB[nt * 16 + l15][quad * 8]);
            acc[nt] = __builtin_amdgcn_mfma_f32_16x16x32_bf16(af, bfr, acc[nt], 0, 0, 0);
        }
    }
    // reduce gate dot across quads (k was split quad-wise): lanes sharing l15
    gdot += __shfl_xor(gdot, 16);
    gdot += __shfl_xor(gdot, 32);
    int bw = b0 + (w >> 1);                 // one b per wave
    float garg = gdot + xk[(size_t)bw * J_DIM + (w & 1) * 16 + l15];
    float gv = 1.f / (1.f + expf(-garg));
    float gate[4];
#pragma unroll
    for (int r = 0; r < 4; ++r) gate[r] = __shfl(gv, quad * 4 + r);
    // epilogue: C/D layout row = quad*4+r, col = nt*16+l15
    float sumsq[4] = {0.f, 0.f, 0.f, 0.f};
    const float* wxrow = wx + (size_t)bw * E_DIM;
#pragma unroll
    for (int nt = 0; nt < 16; ++nt) {
        int f = nt * 16 + l15;
        float wxf = wxrow[f];
#pragma unroll
        for (int r = 0; r < 4; ++r) {
            int rl = quad * 4 + r;
            int jidx = (w & 1) * 16 + rl;
            float c = acc[nt][r] + wxf + vkb[(size_t)jidx * E_DIM + f];
            c = fmaxf(c, 0.f);
            float sv = state[(size_t)(m0 + w * 16 + rl) * E_DIM + f]; // L2-hot re-read
            float t = fmaf(gate[r], c, sv);
            acc[nt][r] = t;
            sumsq[r] += t * t;
        }
    }
    float rn[4];
#pragma unroll
    for (int r = 0; r < 4; ++r) {
        float s2 = sumsq[r];
        s2 += __shfl_xor(s2, 1);
        s2 += __shfl_xor(s2, 2);
        s2 += __shfl_xor(s2, 4);
        s2 += __shfl_xor(s2, 8);
        rn[r] = 1.f / (sqrtf(s2) + 1e-8f);
    }
#pragma unroll
    for (int nt = 0; nt < 16; ++nt)
#pragma unroll
        for (int r = 0; r < 4; ++r)
            out[(size_t)(m0 + w * 16 + quad * 4 + r) * E_DIM + nt * 16 + l15] =
                acc[nt][r] * rn[r];
}

extern "C" void kernel_launch(void* const* d_in, const int* in_sizes, int n_in,
                              void* d_out, int out_size, void* d_ws, size_t ws_size,
                              hipStream_t stream) {
    const float* x     = (const float*)d_in[0];
    const float* state = (const float*)d_in[1];
    const float* keys  = (const float*)d_in[2];
    const float* U     = (const float*)d_in[3];
    const float* V     = (const float*)d_in[4];
    const float* W     = (const float*)d_in[5];
    const float* bias  = (const float*)d_in[6];
    float* out = (float*)d_out;

    float* wsf = (float*)d_ws;
    float* wx  = wsf;                                   // 4096*256 fp32 = 4 MB
    float* xk  = wsf + (size_t)B_DIM * E_DIM;           // 4096*32  fp32 = 512 KB
    float* vkb = xk + (size_t)B_DIM * J_DIM;            // 32*256   fp32 = 32 KB

    xkvkb_kernel<<<544, 256, 0, stream>>>(x, keys, V, bias, xk, vkb);
    wx_kernel<<<256, 256, 0, stream>>>(x, W, wx);
    memcell_kernel<<<M_DIM / BM, 256, 0, stream>>>(x, state, U, wx, xk, vkb, out);
}